// Round 3
// baseline (651.708 us; speedup 1.0000x reference)
//
#include <hip/hip_runtime.h>

// Problem constants (fixed by the reference): B=256, N=2048, D=128, ANCHOR=0
#define B_SZ    256
#define N_NODES 2048
#define D_DIM   128
#define NROW_TOT (B_SZ * N_NODES)   // 524288

typedef __attribute__((ext_vector_type(8))) short short8;   // 8 bf16 = 4 VGPRs (MFMA A/B frag)
typedef __attribute__((ext_vector_type(4))) float f32x4;    // MFMA C/D frag
typedef __attribute__((ext_vector_type(4))) unsigned uint4v;

// ---- workspace layout (bytes) ----
#define WS_W1BF   0          // 128*256 bf16 = 65536
#define WS_COUNT  65536      // 256 * 4
#define WS_T      66560      // 256*128*4 = 131072  (T[b][d] = target_b . W1[d,0:128] + b1[d])
#define WS_ACC    197632     // 256 blocks * 256*128*4 = 33554432 (per-block segment partials)
#define WS_NEEDED (WS_ACC + 256 * B_SZ * D_DIM * 4)

// RNE fp32->bf16 pack of two floats into one uint (lo = first)
__device__ __forceinline__ unsigned pk2(float x, float y) {
    unsigned a = __float_as_uint(x), b = __float_as_uint(y);
    a += 0x7fffu + ((a >> 16) & 1u);
    b += 0x7fffu + ((b >> 16) & 1u);
    return (a >> 16) | (b & 0xffff0000u);
}

// ---- fused prep ----
// blocks  0..63 : W1 -> bf16 (full 128x256; k_main uses k=128..255 half)
// blocks 64..319: T[b][d] = dot(target_b, W1[d][0:128]) + b1[d]   (fp32, 256x128)
__global__ void k_prep(const float* __restrict__ W1, unsigned* __restrict__ w1bf,
                       const float* __restrict__ embs, const float* __restrict__ b1,
                       float* __restrict__ T) {
    int t = threadIdx.x;
    if (blockIdx.x < 64) {
        int i = blockIdx.x * 256 + t;                     // 16384 float2 pairs
        float2 f = ((const float2*)W1)[i];
        w1bf[i] = pk2(f.x, f.y);
        return;
    }
    int tb = blockIdx.x - 64;                             // batch 0..255
    __shared__ float trow[128];
    if (t < 128) trow[t] = embs[(size_t)(tb << 11) * D_DIM + t];
    __syncthreads();
    if (t < 128) {
        const float4* w = (const float4*)(W1 + t * 256);  // W1[d][k], k<128 half
        float s = 0.f;
#pragma unroll
        for (int k = 0; k < 32; k++) {
            float4 wv = w[k];
            s += trow[4 * k + 0] * wv.x + trow[4 * k + 1] * wv.y
               + trow[4 * k + 2] * wv.z + trow[4 * k + 3] * wv.w;
        }
        T[tb * 128 + t] = s + b1[t];
    }
}

// ---- main: STREAMING row order (coalesced), MFMA E = e.W1emb^T, h = relu(E+T[batch]),
// scatter-add h into per-block LDS segment bins (ds_add_f32), flush partials.
// 256 blocks x 512 threads (8 waves, 1 block/CU). No P array, no staging, no main-loop
// barriers: each wave owns a contiguous 256-row span; A-frags built in registers from
// streaming loads (each wave reads contiguous 8KB per 16-row tile).
__global__ __launch_bounds__(512, 2) void k_main(
    const float* __restrict__ embs, const float* __restrict__ Tm,
    const short* __restrict__ w1bf, const int* __restrict__ bidx,
    int* __restrict__ count, float* __restrict__ ACC)
{
    __shared__ float bins[B_SZ * D_DIM];   // 131072 B; rotated: [seg][(d + 4*seg)&127]
    __shared__ int   cbin[B_SZ];

    int tid = threadIdx.x;
    // zero bins (8192 float4) + cbin
#pragma unroll
    for (int i = 0; i < 16; i++)
        ((float4*)bins)[tid + i * 512] = make_float4(0.f, 0.f, 0.f, 0.f);
    if (tid < B_SZ) cbin[tid] = 0;

    int lane = tid & 63;
    int wid  = tid >> 6;       // 0..7
    int q    = lane >> 4;      // quad 0..3
    int i15  = lane & 15;

    // B fragments: emb half of W1: W1[n][128 + kt*32 + q*8 .. +8], n = nt*16 + i15
    short8 bfrag[4][8];
#pragma unroll
    for (int kt = 0; kt < 4; kt++)
#pragma unroll
        for (int nt = 0; nt < 8; nt++)
            bfrag[kt][nt] = *(const short8*)(w1bf + (nt * 16 + i15) * 256 + 128 + kt * 32 + q * 8);

    // my wave's contiguous span: 256 rows, never crosses a 2048-row batch boundary
    int wstart = (blockIdx.x * 8 + wid) * 256;
    int tb = wstart >> 11;     // batch id, constant for the whole span
    float tv[8];
#pragma unroll
    for (int nt = 0; nt < 8; nt++) tv[nt] = Tm[tb * 128 + nt * 16 + i15];

    __syncthreads();           // bins/cbin zero visible

    // lane's streaming base: row (wstart + i15), k-offset q*8 (A-frag layout direct)
    const float* base = embs + (size_t)(wstart + i15) * D_DIM + q * 8;

    float4 raw[8];
#pragma unroll
    for (int kt = 0; kt < 4; kt++) {
        raw[2 * kt]     = *(const float4*)(base + kt * 32);
        raw[2 * kt + 1] = *(const float4*)(base + kt * 32 + 4);
    }

    for (int t = 0; t < 16; t++) {
        // convert current tile's raw floats -> A fragments (in regs, no LDS)
        short8 a[4];
#pragma unroll
        for (int kt = 0; kt < 4; kt++) {
            union { uint4v u; short8 s; } cv;
            float4 lo = raw[2 * kt], hi = raw[2 * kt + 1];
            cv.u = (uint4v){pk2(lo.x, lo.y), pk2(lo.z, lo.w),
                            pk2(hi.x, hi.y), pk2(hi.z, hi.w)};
            a[kt] = cv.s;
        }
        int tilebase = wstart + t * 16;
        int4 sg = *(const int4*)(bidx + tilebase + q * 4);   // segs for rows q*4..q*4+3

        // issue next tile's loads (raw regs now free); land under MFMA + epilogue
        if (t < 15) {
            const float* nb = base + (t + 1) * (16 * D_DIM);
#pragma unroll
            for (int kt = 0; kt < 4; kt++) {
                raw[2 * kt]     = *(const float4*)(nb + kt * 32);
                raw[2 * kt + 1] = *(const float4*)(nb + kt * 32 + 4);
            }
        }

        // MFMA: 16 rows x 128 cols, K=128
        f32x4 acc[8] = {{0,0,0,0},{0,0,0,0},{0,0,0,0},{0,0,0,0},
                        {0,0,0,0},{0,0,0,0},{0,0,0,0},{0,0,0,0}};
#pragma unroll
        for (int kt = 0; kt < 4; kt++)
#pragma unroll
            for (int nt = 0; nt < 8; nt++)
                acc[nt] = __builtin_amdgcn_mfma_f32_16x16x32_bf16(a[kt], bfrag[kt][nt], acc[nt], 0, 0, 0);

        // epilogue: h = relu(E + T), scatter-add into segment bins
#pragma unroll
        for (int j = 0; j < 4; j++) {
            int row = tilebase + q * 4 + j;
            int seg = (&sg.x)[j];
            if ((row & 2047) != 0) {               // skip anchor rows
                if (i15 == 0) atomicAdd(&cbin[seg], 1);
                int rot = (seg << 2);
#pragma unroll
                for (int nt = 0; nt < 8; nt++) {
                    float v = fmaxf(acc[nt][j] + tv[nt], 0.f);
                    atomicAdd(&bins[seg * 128 + ((nt * 16 + i15 + rot) & 127)], v);
                }
            }
        }
    }

    __syncthreads();
    if (tid < B_SZ && cbin[tid]) atomicAdd(&count[tid], cbin[tid]);
    // flush partials (un-rotate), coalesced float4 writes
    float* accout = ACC + (size_t)blockIdx.x * (B_SZ * D_DIM);
#pragma unroll
    for (int i = 0; i < 16; i++) {
        int idx = tid + i * 512;       // float4 index 0..8191
        int s   = idx >> 5;            // 32 float4 per segment
        int d4  = (idx & 31) << 2;
        float4 v = *(const float4*)&bins[s * 128 + ((d4 + (s << 2)) & 127)];
        *(float4*)(accout + s * 128 + d4) = v;
    }
}

// ---- out[s][d] = sum_k (sum_blk ACC[blk][s][k]) * W2[d][k] + cnt[s]*b2[d] ----
__global__ void k_out(const float* __restrict__ ACC, const float* __restrict__ W2,
                      const float* __restrict__ b2, const int* __restrict__ count,
                      float* __restrict__ out) {
    __shared__ float a[D_DIM];
    int s = blockIdx.x, d = threadIdx.x;
    const float* p = ACC + s * D_DIM + d;
    float s0 = 0.f, s1 = 0.f, s2 = 0.f, s3 = 0.f;
#pragma unroll 4
    for (int b = 0; b < 256; b += 4) {
        s0 += p[(size_t)(b + 0) * (B_SZ * D_DIM)];
        s1 += p[(size_t)(b + 1) * (B_SZ * D_DIM)];
        s2 += p[(size_t)(b + 2) * (B_SZ * D_DIM)];
        s3 += p[(size_t)(b + 3) * (B_SZ * D_DIM)];
    }
    a[d] = (s0 + s1) + (s2 + s3);
    __syncthreads();
    float sum = (float)count[s] * b2[d];
    const float4* w = (const float4*)(W2 + d * D_DIM);
#pragma unroll
    for (int k = 0; k < 32; k++) {
        float4 wv = w[k];
        sum += a[4 * k + 0] * wv.x + a[4 * k + 1] * wv.y
             + a[4 * k + 2] * wv.z + a[4 * k + 3] * wv.w;
    }
    out[s * D_DIM + d] = sum;
}

extern "C" void kernel_launch(void* const* d_in, const int* in_sizes, int n_in,
                              void* d_out, int out_size, void* d_ws, size_t ws_size,
                              hipStream_t stream) {
    const float* embs = (const float*)d_in[0];
    const float* W1   = (const float*)d_in[1];
    const float* b1   = (const float*)d_in[2];
    const float* W2   = (const float*)d_in[3];
    const float* b2   = (const float*)d_in[4];
    const int*   bidx = (const int*)d_in[5];

    char* ws = (char*)d_ws;
    unsigned* w1bf_u = (unsigned*)(ws + WS_W1BF);
    short*    w1bf   = (short*)(ws + WS_W1BF);
    int*   count  = (int*)(ws + WS_COUNT);
    float* T      = (float*)(ws + WS_T);
    float* ACC    = (float*)(ws + WS_ACC);

    hipMemsetAsync(count, 0, B_SZ * sizeof(int), stream);
    k_prep<<<320, 256, 0, stream>>>(W1, w1bf_u, embs, b1, T);
    k_main<<<256, 512, 0, stream>>>(embs, T, w1bf, bidx, count, ACC);
    k_out<<<256, 128, 0, stream>>>(ACC, W2, b2, count, (float*)d_out);
}

// Round 4
// 406.011 us; speedup vs baseline: 1.6051x; 1.6051x over previous
//
#include <hip/hip_runtime.h>

// Problem constants (fixed by the reference): B=256, N=2048, D=128, ANCHOR=0
#define B_SZ    256
#define N_NODES 2048
#define D_DIM   128

typedef __attribute__((ext_vector_type(8))) short short8;   // 8 bf16 (MFMA A/B frag)
typedef __attribute__((ext_vector_type(4))) float f32x4;    // MFMA C/D frag

// ---- workspace layout (bytes) ----
#define WS_W1BF   0          // 128*256 bf16 = 65536
#define WS_COUNT  65536      // 256 * 4
#define WS_T      66560      // 256*128*4 = 131072  (T[b][d] = target_b . W1[d,0:128] + b1[d])
#define WS_ACC    197632     // 256 blocks * 256*128*4 = 33554432 (per-block segment partials)
#define WS_NEEDED (WS_ACC + 256 * B_SZ * D_DIM * 4)

// RNE fp32->bf16 pack of two floats into one uint (lo = first)
__device__ __forceinline__ unsigned pk2(float x, float y) {
    unsigned a = __float_as_uint(x), b = __float_as_uint(y);
    a += 0x7fffu + ((a >> 16) & 1u);
    b += 0x7fffu + ((b >> 16) & 1u);
    return (a >> 16) | (b & 0xffff0000u);
}

// one-hot bf16 A-fragment: elem e -> k = q*8+e; 1.0bf16 where bidx==seg.
// killlo masks out elem 0 (the anchor row, once per block).
__device__ __forceinline__ short8 onehot8(int4 c0, int4 c1, int seg, unsigned killlo) {
    union { unsigned u[4]; short8 s; } r;
    r.u[0] = (((c0.x == seg) ? 0x3F80u : 0u) | ((c0.y == seg) ? 0x3F800000u : 0u)) & killlo;
    r.u[1] =  ((c0.z == seg) ? 0x3F80u : 0u) | ((c0.w == seg) ? 0x3F800000u : 0u);
    r.u[2] =  ((c1.x == seg) ? 0x3F80u : 0u) | ((c1.y == seg) ? 0x3F800000u : 0u);
    r.u[3] =  ((c1.z == seg) ? 0x3F80u : 0u) | ((c1.w == seg) ? 0x3F800000u : 0u);
    return r.s;
}

// ---- fused prep ----
// blocks  0..63 : W1 -> bf16 (row-major [d][k], full 128x256)
// blocks 64..319: T[b][d] = dot(target_b, W1[d][0:128]) + b1[d]   (fp32, 256x128)
__global__ void k_prep(const float* __restrict__ W1, unsigned* __restrict__ w1bf,
                       const float* __restrict__ embs, const float* __restrict__ b1,
                       float* __restrict__ T) {
    int t = threadIdx.x;
    if (blockIdx.x < 64) {
        int i = blockIdx.x * 256 + t;                     // 16384 float2 pairs
        float2 f = ((const float2*)W1)[i];
        w1bf[i] = pk2(f.x, f.y);
        return;
    }
    int tb = blockIdx.x - 64;                             // batch 0..255
    __shared__ float trow[128];
    if (t < 128) trow[t] = embs[(size_t)(tb << 11) * D_DIM + t];
    __syncthreads();
    if (t < 128) {
        const float4* w = (const float4*)(W1 + t * 256);  // W1[d][k], k<128 half
        float s = 0.f;
#pragma unroll
        for (int k = 0; k < 32; k++) {
            float4 wv = w[k];
            s += trow[4 * k + 0] * wv.x + trow[4 * k + 1] * wv.y
               + trow[4 * k + 2] * wv.z + trow[4 * k + 3] * wv.w;
        }
        T[tb * 128 + t] = s + b1[t];
    }
}

// ---- main: one block per batch (2048 contiguous rows), 512 threads (8 waves).
// Per 128-row tile: stream rows coalesced -> MFMA h=relu(E.W1emb^T + T) ->
// write h^T (bf16, swizzled) to LDS -> each wave accumulates its 32-segment
// slice via one-hot MFMA (C[seg][d] += onehot[seg][row] * h[row][d]).
// NO atomics in the hot path; one barrier/tile (double-buffered h tile).
__global__ __launch_bounds__(512, 2) void k_main(
    const float* __restrict__ embs, const float* __restrict__ Tm,
    const short* __restrict__ w1bf, const int* __restrict__ bidx,
    int* __restrict__ count, float* __restrict__ ACC)
{
    __shared__ char  w1s[128 * 256];        // 32 KB: W1 emb-half [n][kk] bf16, swizzled
    __shared__ char  ht[2][128 * 256];      // 2x32 KB: h^T [d][r] bf16, swizzled
    __shared__ int   bl[2][128];            // bidx tile (double-buffered)
    __shared__ int   hist[256];

    int tid = threadIdx.x;
    int tb  = blockIdx.x;

    if (tid < 256) hist[tid] = 0;
    // stage W1 emb half -> LDS (byte ^= (n&7)<<4)
#pragma unroll
    for (int i = 0; i < 4; i++) {
        int idx = i * 512 + tid;            // 2048 x 16B
        int n = idx >> 4, k16 = idx & 15;
        uint4 v = *(const uint4*)(w1bf + n * 256 + 128 + k16 * 8);
        *(uint4*)(w1s + ((n * 256 + k16 * 16) ^ ((n & 7) << 4))) = v;
    }

    int lane = tid & 63, wid = tid >> 6, q = lane >> 4, i15 = lane & 15;
    unsigned swz = (unsigned)(i15 & 7) << 4;

    float tv[8];
#pragma unroll
    for (int nt = 0; nt < 8; nt++) tv[nt] = Tm[tb * 128 + nt * 16 + i15];

    f32x4 acc[2][8];
#pragma unroll
    for (int st = 0; st < 2; st++)
#pragma unroll
        for (int dt = 0; dt < 8; dt++) acc[st][dt] = (f32x4){0.f, 0.f, 0.f, 0.f};

    // streaming base: wave wid owns rows wid*16..+15 of each 128-row tile
    const float* base = embs + ((size_t)tb * N_NODES + wid * 16 + i15) * D_DIM + q * 8;

    // prefetch tile 0
    float4 raw[8];
#pragma unroll
    for (int kt = 0; kt < 4; kt++) {
        raw[2 * kt]     = *(const float4*)(base + kt * 32);
        raw[2 * kt + 1] = *(const float4*)(base + kt * 32 + 4);
    }
    int4 ib = {0, 0, 0, 0};
    if (tid < 32) ib = *(const int4*)(bidx + tb * N_NODES + tid * 4);

    __syncthreads();   // w1s + hist ready

    for (int t = 0; t < 16; t++) {
        char* hb = ht[t & 1];
        int*  bb = bl[t & 1];

        // ---- phase 1: bidx tile + histogram ----
        if (tid < 32) {
            *(int4*)&bb[tid * 4] = ib;
            if (t | tid) atomicAdd(&hist[ib.x], 1);   // skip anchor (local row 0)
            atomicAdd(&hist[ib.y], 1);
            atomicAdd(&hist[ib.z], 1);
            atomicAdd(&hist[ib.w], 1);
        }

        // convert streamed rows -> A fragments
        short8 a[4];
#pragma unroll
        for (int kt = 0; kt < 4; kt++) {
            union { unsigned u[4]; short8 s; } cv;
            float4 lo = raw[2 * kt], hi = raw[2 * kt + 1];
            cv.u[0] = pk2(lo.x, lo.y); cv.u[1] = pk2(lo.z, lo.w);
            cv.u[2] = pk2(hi.x, hi.y); cv.u[3] = pk2(hi.z, hi.w);
            a[kt] = cv.s;
        }

        int nz = 0;
        asm volatile("" : "+v"(nz));      // defeat LICM: keep W1 frags out of regs
        const char* w1p = w1s + nz;

        // h-GEMM: E[16 rows][128 cols], K=128
        f32x4 m[8];
#pragma unroll
        for (int nt = 0; nt < 8; nt++) m[nt] = (f32x4){0.f, 0.f, 0.f, 0.f};
#pragma unroll
        for (int kt = 0; kt < 4; kt++)
#pragma unroll
            for (int nt = 0; nt < 8; nt++) {
                short8 b = *(const short8*)(w1p +
                    (((nt * 16 + i15) * 256 + kt * 64 + q * 16) ^ swz));
                m[nt] = __builtin_amdgcn_mfma_f32_16x16x32_bf16(a[kt], b, m[nt], 0, 0, 0);
            }

        // h = relu(E + T) -> bf16, 4 rows packed per b64 write to ht[d][r]
#pragma unroll
        for (int nt = 0; nt < 8; nt++) {
            float h0 = fmaxf(m[nt][0] + tv[nt], 0.f);
            float h1 = fmaxf(m[nt][1] + tv[nt], 0.f);
            float h2 = fmaxf(m[nt][2] + tv[nt], 0.f);
            float h3 = fmaxf(m[nt][3] + tv[nt], 0.f);
            uint2 pw = make_uint2(pk2(h0, h1), pk2(h2, h3));
            *(uint2*)(hb + (((nt * 16 + i15) * 256 + wid * 32 + q * 8) ^ swz)) = pw;
        }

        // issue next tile's stream loads (land under the one-hot phase)
        if (t < 15) {
            const float* nb = base + (t + 1) * (128 * D_DIM);
#pragma unroll
            for (int kt = 0; kt < 4; kt++) {
                raw[2 * kt]     = *(const float4*)(nb + kt * 32);
                raw[2 * kt + 1] = *(const float4*)(nb + kt * 32 + 4);
            }
            if (tid < 32) ib = *(const int4*)(bidx + tb * N_NODES + (t + 1) * 128 + tid * 4);
        }

        __syncthreads();   // single barrier per tile (double-buffered ht/bl)

        // ---- phase 2: one-hot MFMA into per-wave 32-seg slice ----
        int seg0 = wid * 32 + i15;
        unsigned kl = (t == 0 && q == 0) ? 0xFFFF0000u : 0xFFFFFFFFu;
#pragma unroll
        for (int kt = 0; kt < 4; kt++) {
            int4 c0 = *(const int4*)&bb[kt * 32 + q * 8];
            int4 c1 = *(const int4*)&bb[kt * 32 + q * 8 + 4];
            unsigned klk = (kt == 0) ? kl : 0xFFFFFFFFu;
            short8 A0 = onehot8(c0, c1, seg0, klk);
            short8 A1 = onehot8(c0, c1, seg0 + 16, klk);
#pragma unroll
            for (int dt = 0; dt < 8; dt++) {
                short8 hf = *(const short8*)(hb +
                    (((dt * 16 + i15) * 256 + kt * 64 + q * 16) ^ swz));
                acc[0][dt] = __builtin_amdgcn_mfma_f32_16x16x32_bf16(A0, hf, acc[0][dt], 0, 0, 0);
                acc[1][dt] = __builtin_amdgcn_mfma_f32_16x16x32_bf16(A1, hf, acc[1][dt], 0, 0, 0);
            }
        }
    }

    __syncthreads();
    if (tid < 256 && hist[tid]) atomicAdd(&count[tid], hist[tid]);

    // flush: wave wid owns segs wid*32..+31; C row m=q*4+j -> seg, col n=i15 -> d
    float* aout = ACC + (size_t)tb * (B_SZ * D_DIM);
#pragma unroll
    for (int st = 0; st < 2; st++)
#pragma unroll
        for (int dt = 0; dt < 8; dt++)
#pragma unroll
            for (int j = 0; j < 4; j++)
                aout[(wid * 32 + st * 16 + q * 4 + j) * 128 + dt * 16 + i15] = acc[st][dt][j];
}

// ---- out[s][d] = sum_k (sum_blk ACC[blk][s][k]) * W2[d][k] + cnt[s]*b2[d] ----
__global__ void k_out(const float* __restrict__ ACC, const float* __restrict__ W2,
                      const float* __restrict__ b2, const int* __restrict__ count,
                      float* __restrict__ out) {
    __shared__ float a[D_DIM];
    int s = blockIdx.x, d = threadIdx.x;
    const float* p = ACC + s * D_DIM + d;
    float s0 = 0.f, s1 = 0.f, s2 = 0.f, s3 = 0.f;
#pragma unroll 4
    for (int b = 0; b < 256; b += 4) {
        s0 += p[(size_t)(b + 0) * (B_SZ * D_DIM)];
        s1 += p[(size_t)(b + 1) * (B_SZ * D_DIM)];
        s2 += p[(size_t)(b + 2) * (B_SZ * D_DIM)];
        s3 += p[(size_t)(b + 3) * (B_SZ * D_DIM)];
    }
    a[d] = (s0 + s1) + (s2 + s3);
    __syncthreads();
    float sum = (float)count[s] * b2[d];
    const float4* w = (const float4*)(W2 + d * D_DIM);
#pragma unroll
    for (int k = 0; k < 32; k++) {
        float4 wv = w[k];
        sum += a[4 * k + 0] * wv.x + a[4 * k + 1] * wv.y
             + a[4 * k + 2] * wv.z + a[4 * k + 3] * wv.w;
    }
    out[s * D_DIM + d] = sum;
}

extern "C" void kernel_launch(void* const* d_in, const int* in_sizes, int n_in,
                              void* d_out, int out_size, void* d_ws, size_t ws_size,
                              hipStream_t stream) {
    const float* embs = (const float*)d_in[0];
    const float* W1   = (const float*)d_in[1];
    const float* b1   = (const float*)d_in[2];
    const float* W2   = (const float*)d_in[3];
    const float* b2   = (const float*)d_in[4];
    const int*   bidx = (const int*)d_in[5];

    char* ws = (char*)d_ws;
    unsigned* w1bf_u = (unsigned*)(ws + WS_W1BF);
    short*    w1bf   = (short*)(ws + WS_W1BF);
    int*   count  = (int*)(ws + WS_COUNT);
    float* T      = (float*)(ws + WS_T);
    float* ACC    = (float*)(ws + WS_ACC);

    hipMemsetAsync(count, 0, B_SZ * sizeof(int), stream);
    k_prep<<<320, 256, 0, stream>>>(W1, w1bf_u, embs, b1, T);
    k_main<<<256, 512, 0, stream>>>(embs, T, w1bf, bidx, count, ACC);
    k_out<<<256, 128, 0, stream>>>(ACC, W2, b2, count, (float*)d_out);
}